// Round 3
// baseline (12375.291 us; speedup 1.0000x reference)
//
#include <hip/hip_runtime.h>

// ---------------------------------------------------------------------------
// RMT layer: B=16 chains x NM=64 sequential steps.
// Round 3: ONE persistent kernel runs all 64 steps (grid 256 x 512thr,
// 1 block/CU guaranteed by 100KB LDS) with a hand-rolled device-scope grid
// barrier (3/step). x-row K/V GEMM folded into phase B (computed 1 step
// ahead); k_kvx deleted. All math chains bit-identical to round 1/2
// (absmax 0.078125): ascending-32 K-chunk MFMA order, identical LN
// reduction trees, identical rounding points.
// ---------------------------------------------------------------------------

typedef __attribute__((ext_vector_type(8))) _Float16 f16x8;
typedef __attribute__((ext_vector_type(4))) _Float16 f16x4;
typedef __attribute__((ext_vector_type(8))) short    s16x8;
typedef __attribute__((ext_vector_type(4))) float    f32x4;

#define NB   16
#define NMs  64
#define MBs  64
#define Dm   1024
#define NHh  16
#define NKVh 8
#define MEMm 64

// ---------------- static device scratch ------------------------------------
__device__ __align__(16) _Float16      g_W1t[2048 * 1024];   // [n][k]: 0..1023 q, 1024..1535 k, 1536..2047 v
__device__ __align__(16) _Float16      g_Wot[1024 * 1024];   // wo^T [n][k]
__device__ __align__(16) float         g_rc[128 * 32];
__device__ __align__(16) float         g_rs[128 * 32];
__device__                unsigned char g_mask[NB * NMs];
__device__ __align__(16) _Float16      g_hx[(size_t)NB * NMs * MBs * Dm]; // LN'd x rows, f16
__device__ __align__(16) _Float16      g_hmem[NB * MEMm * Dm];            // LN'd mem rows, f16
__device__ __align__(16) float         g_memA[NB * MEMm * Dm];
__device__ __align__(16) float         g_memB[NB * MEMm * Dm];
// x-row K/V: [s][b][kvh][pos0..63][d]  bf16
__device__ __align__(16) unsigned short g_kx[(size_t)NMs * NB * NKVh * 64 * 64];
__device__ __align__(16) unsigned short g_vx[(size_t)NMs * NB * NKVh * 64 * 64];
__device__ __align__(16) _Float16      g_enc[NB * 64 * Dm];           // attention out, f16
__device__ __align__(16) float         g_outp[NB * 64 * Dm];          // enc @ wo, fp32
// grid barrier state (zero-init at load; self-cleaning across calls)
__device__ unsigned g_leaf[8];
__device__ unsigned g_root;
__device__ unsigned g_gen;

// ---------------- helpers ---------------------------------------------------
__device__ __forceinline__ unsigned short f2bf(float x) {
    union { float f; unsigned u; } v; v.f = x;
    unsigned u = v.u;
    return (unsigned short)((u + 0x7fffu + ((u >> 16) & 1u)) >> 16);  // RNE
}
__device__ __forceinline__ float bf2f(unsigned short h) {
    union { unsigned u; float f; } v; v.u = ((unsigned)h) << 16; return v.f;
}

__device__ __forceinline__ void gload_lds16(const void* g, void* l) {
    __builtin_amdgcn_global_load_lds(
        (const __attribute__((address_space(1))) unsigned int*)g,
        (__attribute__((address_space(3))) unsigned int*)l, 16, 0, 0);
}

// two-level grid barrier: 256 blocks, 8 leaves x 32 + root + generation
__device__ __forceinline__ void grid_barrier(int bid, unsigned tgt) {
    __syncthreads();
    if (threadIdx.x == 0) {
        __threadfence();                          // release: drain stores, wb L2
        unsigned v = atomicAdd(&g_leaf[bid & 7], 1u);
        if (v == 31u) {
            unsigned r = atomicAdd(&g_root, 1u);
            if (r == 7u) {
                #pragma unroll
                for (int i = 0; i < 8; i++) atomicExch(&g_leaf[i], 0u);
                atomicExch(&g_root, 0u);
                __threadfence();                  // resets performed before gen bump
                atomicAdd(&g_gen, 1u);
            }
        }
        while ((int)(__hip_atomic_load(&g_gen, __ATOMIC_ACQUIRE,
                                       __HIP_MEMORY_SCOPE_AGENT) - tgt) < 0)
            __builtin_amdgcn_s_sleep(2);
        __threadfence();                          // acquire: invalidate L1/L2
    }
    __syncthreads();
}

// 512-thread variant of round-2 block_stats: two independent 256-thread
// groups, each with the EXACT round-2 reduction tree (bitwise identical).
__device__ __forceinline__ void block_stats512(int tid, float (*red)[8],
        float s, float ss, float eps, float* mean, float* rstd) {
    for (int off = 32; off > 0; off >>= 1) {
        s  += __shfl_down(s, off);
        ss += __shfl_down(ss, off);
    }
    int g = tid >> 8, wid = (tid >> 6) & 3, lane = tid & 63;
    __syncthreads();
    if (lane == 0) { red[g][wid] = s; red[g][4 + wid] = ss; }
    __syncthreads();
    float ts  = red[g][0] + red[g][1] + red[g][2] + red[g][3];
    float tss = red[g][4] + red[g][5] + red[g][6] + red[g][7];
    float m   = ts * (1.0f / 1024.0f);
    float var = tss * (1.0f / 1024.0f) - m * m;
    *mean = m;
    *rstd = rsqrtf(var + eps);
}

// 256-thread version (init kernels, unchanged from round 2)
__device__ __forceinline__ void block_stats(float s, float ss, float eps,
                                            float* mean, float* rstd) {
    for (int off = 32; off > 0; off >>= 1) {
        s  += __shfl_down(s, off);
        ss += __shfl_down(ss, off);
    }
    __shared__ float red[8];
    int wid = threadIdx.x >> 6, lane = threadIdx.x & 63;
    __syncthreads();
    if (lane == 0) { red[wid] = s; red[4 + wid] = ss; }
    __syncthreads();
    float ts  = red[0] + red[1] + red[2] + red[3];
    float tss = red[4] + red[5] + red[6] + red[7];
    float m   = ts * (1.0f / 1024.0f);
    float var = tss * (1.0f / 1024.0f) - m * m;
    *mean = m;
    *rstd = rsqrtf(var + eps);
}

// ---------------- init kernels (unchanged math) -----------------------------
__global__ void k_transpose(const float* __restrict__ in, int ncols, int dsel) {
    _Float16* out = (dsel == 0) ? g_W1t
                  : (dsel == 1) ? (g_W1t + 1024 * 1024)
                  : (dsel == 2) ? (g_W1t + 1536 * 1024)
                                : g_Wot;
    __shared__ float tile[64][65];
    int bk = blockIdx.x, bn = blockIdx.y;
    int c = threadIdx.x & 63, rg = threadIdx.x >> 6;
    int k0 = bk * 64, n0 = bn * 64;
    for (int i = 0; i < 16; i++) {
        int r = rg * 16 + i;
        tile[r][c] = in[(size_t)(k0 + r) * ncols + n0 + c];
    }
    __syncthreads();
    for (int i = 0; i < 16; i++) {
        int r = rg * 16 + i;
        out[(size_t)(n0 + r) * 1024 + k0 + c] = (_Float16)tile[c][r];
    }
}

__global__ void k_rope() {
    int t = threadIdx.x;
    for (int j = 0; j < 32; j++) {
        double f = pow(10000.0, -(double)j / 32.0);
        double a = (double)t * f;
        g_rc[t * 32 + j] = (float)cos(a);
        g_rs[t * 32 + j] = (float)sin(a);
    }
}

__global__ void k_mask(const unsigned int* __restrict__ ip) {
    __shared__ int byteFmt;
    int t = threadIdx.x;
    if (t == 0) byteFmt = 0;
    __syncthreads();
    if (t < 256) {
        unsigned v = ip[t];
        if (!(v == 0u || v == 1u || v == 0x3F800000u)) byteFmt = 1;
    }
    __syncthreads();
    unsigned char m = byteFmt ? (((const unsigned char*)ip)[t] != 0)
                              : (ip[t] != 0u);
    g_mask[t] = m;
}

__global__ void k_ln_hx(const float* __restrict__ x,
                        const float* __restrict__ sc, const float* __restrict__ bi) {
    size_t row = blockIdx.x;
    int t = threadIdx.x;
    float4 v = ((const float4*)(x + row * 1024))[t];
    float mean, rstd;
    block_stats(v.x + v.y + v.z + v.w,
                v.x * v.x + v.y * v.y + v.z * v.z + v.w * v.w, 1e-6f, &mean, &rstd);
    float4 s4 = ((const float4*)sc)[t];
    float4 b4 = ((const float4*)bi)[t];
    f16x4 o;
    o[0] = (_Float16)((v.x - mean) * rstd * s4.x + b4.x);
    o[1] = (_Float16)((v.y - mean) * rstd * s4.y + b4.y);
    o[2] = (_Float16)((v.z - mean) * rstd * s4.z + b4.z);
    o[3] = (_Float16)((v.w - mean) * rstd * s4.w + b4.w);
    *(f16x4*)(g_hx + row * 1024 + t * 4) = o;
}

__global__ void k_ln_init(const float* __restrict__ ms,
                          const float* __restrict__ sc, const float* __restrict__ bi) {
    int b = blockIdx.x >> 6, r = blockIdx.x & 63;
    int t = threadIdx.x;
    float4 v = ((const float4*)(ms + (size_t)r * 1024))[t];
    ((float4*)(g_memA + ((size_t)b * 64 + r) * 1024))[t] = v;
    float mean, rstd;
    block_stats(v.x + v.y + v.z + v.w,
                v.x * v.x + v.y * v.y + v.z * v.z + v.w * v.w, 1e-6f, &mean, &rstd);
    float4 s4 = ((const float4*)sc)[t];
    float4 b4 = ((const float4*)bi)[t];
    f16x4 o;
    o[0] = (_Float16)((v.x - mean) * rstd * s4.x + b4.x);
    o[1] = (_Float16)((v.y - mean) * rstd * s4.y + b4.y);
    o[2] = (_Float16)((v.z - mean) * rstd * s4.z + b4.z);
    o[3] = (_Float16)((v.w - mean) * rstd * s4.w + b4.w);
    *(f16x4*)(g_hmem + ((size_t)b * 64 + r) * 1024 + t * 4) = o;
}

// ---------------------------------------------------------------------------
// Phase B body (shared by persistent kernel and prefill kernel).
// 512 threads: waves (mt 0..3, sel 0..1). sel0 = gemm2 (enc@wo tile, s>=0),
// sel1 = x-row K/V for step ss (<64). Both: M=64, N=64, K=1024, BK=128,
// staged B (32KB LDS at sm), A direct from global. Chains ascending-32.
// ---------------------------------------------------------------------------
__device__ __forceinline__ void phaseB_body(int s, int ss, int b, int nt16,
                                            int tid, char* sm) {
    int w = tid >> 6, l = tid & 63;
    int fr = l & 15, kc = l >> 4, quad = kc;
    int mt = w & 3, sel = w >> 2;
    int ssc = (ss < 64) ? ss : 63;
    bool active = (sel == 0) ? (s >= 0) : (ss < 64);
    const _Float16* A = (sel == 0)
        ? (g_enc + (size_t)b * 64 * 1024)
        : (g_hx + (((size_t)b * 64 + ssc) * 64) * 1024);
    f32x4 acc[4];
    #pragma unroll
    for (int i = 0; i < 4; i++) acc[i] = (f32x4){0.f, 0.f, 0.f, 0.f};

    for (int kt = 0; kt < 8; ++kt) {
        #pragma unroll
        for (int jj = 0; jj < 4; ++jj) {
            int m = w * 4 + jj;                 // 0..31
            int tile = m >> 4, m4 = m & 15, rg = m4 & 3, kq = m4 >> 2;
            if (tile == 0) {
                if (s >= 0)
                    gload_lds16(g_Wot + (size_t)(nt16 * 64 + rg * 16 + fr) * 1024
                                + kt * 128 + kq * 32 + kc * 8, sm + m * 1024);
            } else {
                if (ss < 64)
                    gload_lds16(g_W1t + (size_t)(1024 + nt16 * 64 + rg * 16 + fr) * 1024
                                + kt * 128 + kq * 32 + kc * 8, sm + m * 1024);
            }
        }
        f16x8 a[4];
        if (active) {
            #pragma unroll
            for (int ci = 0; ci < 4; ci++)
                a[ci] = *(const f16x8*)(A + (size_t)(mt * 16 + fr) * 1024
                                        + kt * 128 + ci * 32 + kc * 8);
        }
        __syncthreads();
        if (active) {
            #pragma unroll
            for (int nt = 0; nt < 4; ++nt) {
                #pragma unroll
                for (int ci = 0; ci < 4; ++ci) {
                    f16x8 bf = *(const f16x8*)(sm + (size_t)((sel << 4) + nt + 4 * ci) * 1024 + l * 16);
                    acc[nt] = __builtin_amdgcn_mfma_f32_16x16x32_f16(a[ci], bf, acc[nt], 0, 0, 0);
                }
            }
        }
        __syncthreads();
    }

    if (sel == 0 && s >= 0) {
        #pragma unroll
        for (int nt = 0; nt < 4; nt++)
            #pragma unroll
            for (int r = 0; r < 4; r++)
                g_outp[((size_t)b * 64 + mt * 16 + quad * 4 + r) * 1024
                       + nt16 * 64 + nt * 16 + fr] = acc[nt][r];
    } else if (sel == 1 && ss < 64) {
        #pragma unroll
        for (int nt = 0; nt < 4; nt++)
            #pragma unroll
            for (int r = 0; r < 4; r++) {
                float val = acc[nt][r];
                float p = __shfl_xor(val, 1);
                int row = mt * 16 + quad * 4 + r;          // pos 0..63
                int col = nt16 * 64 + nt * 16 + fr;        // kv col 0..1023
                int d = col & 63;
                if (col < 512) {                           // k: RoPE at pos=row
                    int kvh = col >> 6, j2 = d >> 1;
                    float cc = g_rc[row * 32 + j2], sn = g_rs[row * 32 + j2];
                    float o = (d & 1) ? (p * sn + val * cc) : (val * cc - p * sn);
                    g_kx[(((size_t)ss * 16 + b) * 8 + kvh) * 4096 + row * 64 + d] = f2bf(o);
                } else {                                   // v
                    int kvh = (col - 512) >> 6;
                    g_vx[(((size_t)ss * 16 + b) * 8 + kvh) * 4096 + row * 64 + d] = f2bf(val);
                }
            }
    }
}

// prefill: x-row K/V for step 0 only
__global__ __launch_bounds__(512) void k_xkv0() {
    __shared__ __align__(16) char sm[32768];
    phaseB_body(-1, 0, blockIdx.x >> 4, blockIdx.x & 15, threadIdx.x, sm);
}

// ---------------------------------------------------------------------------
// Persistent kernel: all 64 steps. 256 blocks x 512 threads, ~100KB LDS
// (1 block/CU => co-residency guaranteed). 3 grid barriers per step.
// ---------------------------------------------------------------------------
#define SM_QS  49152
#define SM_KS  58368
#define SM_VT  67584
#define SM_PS  84992
#define SM_TOT 102400

__global__ __launch_bounds__(512, 1) void k_loop(float* __restrict__ dout,
        const float* __restrict__ post_s, const float* __restrict__ post_b,
        const float* __restrict__ pre_s,  const float* __restrict__ pre_b) {
    __shared__ __align__(16) char smem[SM_TOT];
    __shared__ float red2[2][8];
    const int bid = blockIdx.x;
    const int tid = threadIdx.x;
    const int w = tid >> 6, l = tid & 63;
    const int fr = l & 15, kc = l >> 4, quad = kc;
    const int b = bid >> 4, hn = bid & 15;   // h (phase A) / ntile (B) / rquad (C)
    unsigned gbase = __hip_atomic_load(&g_gen, __ATOMIC_RELAXED, __HIP_MEMORY_SCOPE_AGENT);
    unsigned nbar = 0;

    unsigned short* q_s  = (unsigned short*)(smem + SM_QS);
    unsigned short* k_s  = (unsigned short*)(smem + SM_KS);
    unsigned short* vt_s = (unsigned short*)(smem + SM_VT);
    unsigned short* p_s  = (unsigned short*)(smem + SM_PS);

    for (int s = 0; s < NMs; ++s) {
        // ================= phase A: QKV(mem)+RoPE+attention -> enc =========
        {
            const int h = hn, kvh = h >> 1;
            const unsigned short* vx = g_vx + (((size_t)s * 16 + b) * 8 + kvh) * 4096;
            const unsigned short* kx = g_kx + (((size_t)s * 16 + b) * 8 + kvh) * 4096;
            {   // prestage vt_s x-part: [d][pos] from vx [pos][d]
                int pos = tid & 63, dg = tid >> 6;
                ushort4 u0 = *(const ushort4*)(vx + pos * 64 + dg * 8);
                ushort4 u1 = *(const ushort4*)(vx + pos * 64 + dg * 8 + 4);
                vt_s[(dg * 8 + 0) * 136 + pos] = u0.x;
                vt_s[(dg * 8 + 1) * 136 + pos] = u0.y;
                vt_s[(dg * 8 + 2) * 136 + pos] = u0.z;
                vt_s[(dg * 8 + 3) * 136 + pos] = u0.w;
                vt_s[(dg * 8 + 4) * 136 + pos] = u1.x;
                vt_s[(dg * 8 + 5) * 136 + pos] = u1.y;
                vt_s[(dg * 8 + 6) * 136 + pos] = u1.z;
                vt_s[(dg * 8 + 7) * 136 + pos] = u1.w;
            }
            const _Float16* A = g_hmem + (size_t)b * 64 * 1024;
            const int mt = w & 3, nh = w >> 2;
            f32x4 acc[6];
            #pragma unroll
            for (int i = 0; i < 6; i++) acc[i] = (f32x4){0.f, 0.f, 0.f, 0.f};
            const int browQ = h * 64, browK = 1024 + kvh * 64, browV = 1536 + kvh * 64;

            for (int kt = 0; kt < 8; ++kt) {
                #pragma unroll
                for (int jj = 0; jj < 6; ++jj) {
                    int m = w * 6 + jj;                   // 0..47
                    int rg = m % 12, kq = m / 12;
                    int r192 = rg * 16 + fr;
                    int brow = (r192 < 64) ? (browQ + r192)
                             : (r192 < 128) ? (browK + r192 - 64)
                                            : (browV + r192 - 128);
                    gload_lds16(g_W1t + (size_t)brow * 1024 + kt * 128 + kq * 32 + kc * 8,
                                smem + m * 1024);
                }
                f16x8 a[4];
                #pragma unroll
                for (int ci = 0; ci < 4; ci++)
                    a[ci] = *(const f16x8*)(A + (size_t)(mt * 16 + fr) * 1024
                                            + kt * 128 + ci * 32 + kc * 8);
                __syncthreads();
                #pragma unroll
                for (int ntl = 0; ntl < 6; ++ntl) {
                    int ntG = nh * 6 + ntl;
                    #pragma unroll
                    for (int ci = 0; ci < 4; ++ci) {
                        f16x8 bf = *(const f16x8*)(smem + (size_t)(ntG + 12 * ci) * 1024 + l * 16);
                        acc[ntl] = __builtin_amdgcn_mfma_f32_16x16x32_f16(a[ci], bf, acc[ntl], 0, 0, 0);
                    }
                }
                __syncthreads();
            }
            // epilogue: RoPE + bf16 -> q_s / k_s / vt_s mem part
            #pragma unroll
            for (int ntl = 0; ntl < 6; ++ntl) {
                #pragma unroll
                for (int r = 0; r < 4; ++r) {
                    float val = acc[ntl][r];
                    float p = __shfl_xor(val, 1);
                    int row = mt * 16 + quad * 4 + r;     // mem index 0..63
                    int col = (nh * 6 + ntl) * 16 + fr;   // 0..191
                    if (col < 128) {
                        int d = col & 63, pos = 64 + row, j2 = d >> 1;
                        float cc = g_rc[pos * 32 + j2], sn = g_rs[pos * 32 + j2];
                        float o = (d & 1) ? (p * sn + val * cc) : (val * cc - p * sn);
                        unsigned short bo = f2bf(o);
                        if (col < 64) q_s[row * 72 + d] = bo;
                        else          k_s[row * 72 + d] = bo;
                    } else {
                        int d = col - 128;
                        vt_s[d * 136 + 64 + row] = f2bf(val);
                    }
                }
            }
            __syncthreads();
            if (w < 4) {   // attention: waves 0..3, exactly round-2 structure
                s16x8 qa0 = *(const s16x8*)&q_s[(w * 16 + fr) * 72 + kc * 8];
                s16x8 qa1 = *(const s16x8*)&q_s[(w * 16 + fr) * 72 + 32 + kc * 8];
                f32x4 sc2[8];
                #pragma unroll
                for (int nt = 0; nt < 8; ++nt) {
                    sc2[nt] = (f32x4){0.f, 0.f, 0.f, 0.f};
                    s16x8 kb0, kb1;
                    if (nt < 4) {
                        kb0 = *(const s16x8*)(kx + (nt * 16 + fr) * 64 + kc * 8);
                        kb1 = *(const s16x8*)(kx + (nt * 16 + fr) * 64 + 32 + kc * 8);
                    } else {
                        kb0 = *(const s16x8*)&k_s[((nt - 4) * 16 + fr) * 72 + kc * 8];
                        kb1 = *(const s16x8*)&k_s[((nt - 4) * 16 + fr) * 72 + 32 + kc * 8];
                    }
                    sc2[nt] = __builtin_amdgcn_mfma_f32_16x16x32_bf16(qa0, kb0, sc2[nt], 0, 0, 0);
                    sc2[nt] = __builtin_amdgcn_mfma_f32_16x16x32_bf16(qa1, kb1, sc2[nt], 0, 0, 0);
                }
                float lv[8][4];
                #pragma unroll
                for (int nt = 0; nt < 8; nt++)
                    #pragma unroll
                    for (int r = 0; r < 4; r++)
                        lv[nt][r] = bf2f(f2bf(sc2[nt][r])) * 0.125f;
                unsigned short* pw = p_s + w * 16 * 136;
                #pragma unroll
                for (int r = 0; r < 4; r++) {
                    float mx = -1e30f;
                    #pragma unroll
                    for (int nt = 0; nt < 8; nt++) mx = fmaxf(mx, lv[nt][r]);
                    for (int off = 1; off < 16; off <<= 1) mx = fmaxf(mx, __shfl_xor(mx, off));
                    float sm2 = 0.f;
                    #pragma unroll
                    for (int nt = 0; nt < 8; nt++) { lv[nt][r] = expf(lv[nt][r] - mx); sm2 += lv[nt][r]; }
                    for (int off = 1; off < 16; off <<= 1) sm2 += __shfl_xor(sm2, off);
                    float inv = 1.0f / sm2;
                    int row = quad * 4 + r;
                    #pragma unroll
                    for (int nt = 0; nt < 8; nt++)
                        pw[row * 136 + nt * 16 + fr] = f2bf(lv[nt][r] * inv);
                }
                f32x4 o[4];
                #pragma unroll
                for (int nt = 0; nt < 4; nt++) o[nt] = (f32x4){0.f, 0.f, 0.f, 0.f};
                for (int kt2 = 0; kt2 < 4; ++kt2) {
                    s16x8 pa = *(const s16x8*)&pw[fr * 136 + kt2 * 32 + kc * 8];
                    #pragma unroll
                    for (int nt = 0; nt < 4; ++nt) {
                        s16x8 vb = *(const s16x8*)&vt_s[(nt * 16 + fr) * 136 + kt2 * 32 + kc * 8];
                        o[nt] = __builtin_amdgcn_mfma_f32_16x16x32_bf16(pa, vb, o[nt], 0, 0, 0);
                    }
                }
                #pragma unroll
                for (int nt = 0; nt < 4; nt++)
                    #pragma unroll
                    for (int r = 0; r < 4; r++) {
                        int m = w * 16 + quad * 4 + r;
                        int d = nt * 16 + fr;
                        g_enc[((size_t)b * 64 + m) * 1024 + h * 64 + d] =
                            (_Float16)bf2f(f2bf(o[nt][r]));
                    }
            }
        }
        grid_barrier(bid, gbase + (++nbar));

        // ================= phase B: gemm2 + next step's x-kv ===============
        phaseB_body(s, s + 1, b, hn, tid, smem);
        grid_barrier(bid, gbase + (++nbar));

        // ================= phase C: ln2 (4 rows/block) =====================
        {
            const float* memIn = (s & 1) ? g_memB : g_memA;
            float* memOut = (s == 63) ? dout : ((s & 1) ? g_memA : g_memB);
            int g = tid >> 8, tl = tid & 255;
            #pragma unroll
            for (int rr = 0; rr < 2; ++rr) {
                int r = hn * 4 + g * 2 + rr;
                size_t row = (size_t)b * 64 + r;
                float4 ov = ((const float4*)(g_outp + row * 1024))[tl];
                float4 mv = ((const float4*)(memIn + row * 1024))[tl];
                float4 y = {ov.x + mv.x, ov.y + mv.y, ov.z + mv.z, ov.w + mv.w};
                float mean, rstd;
                block_stats512(tid, red2,
                               y.x + y.y + y.z + y.w,
                               y.x * y.x + y.y * y.y + y.z * y.z + y.w * y.w,
                               1e-6f, &mean, &rstd);
                float4 s4 = ((const float4*)post_s)[tl];
                float4 b4 = ((const float4*)post_b)[tl];
                float4 nm = {(y.x - mean) * rstd * s4.x + b4.x,
                             (y.y - mean) * rstd * s4.y + b4.y,
                             (y.z - mean) * rstd * s4.z + b4.z,
                             (y.w - mean) * rstd * s4.w + b4.w};
                int mk = g_mask[b * 64 + s];
                float4 sel4 = mk ? nm : mv;
                ((float4*)(memOut + row * 1024))[tl] = sel4;
                float m2, rs2;
                block_stats512(tid, red2,
                               sel4.x + sel4.y + sel4.z + sel4.w,
                               sel4.x * sel4.x + sel4.y * sel4.y + sel4.z * sel4.z + sel4.w * sel4.w,
                               1e-6f, &m2, &rs2);
                float4 c4 = ((const float4*)pre_s)[tl];
                float4 d4 = ((const float4*)pre_b)[tl];
                f16x4 o;
                o[0] = (_Float16)((sel4.x - m2) * rs2 * c4.x + d4.x);
                o[1] = (_Float16)((sel4.y - m2) * rs2 * c4.y + d4.y);
                o[2] = (_Float16)((sel4.z - m2) * rs2 * c4.z + d4.z);
                o[3] = (_Float16)((sel4.w - m2) * rs2 * c4.w + d4.w);
                *(f16x4*)(g_hmem + row * 1024 + tl * 4) = o;
            }
        }
        if (s != 63) grid_barrier(bid, gbase + (++nbar));
    }
}

// ---------------------------------------------------------------------------
extern "C" void kernel_launch(void* const* d_in, const int* in_sizes, int n_in,
                              void* d_out, int out_size, void* d_ws, size_t ws_size,
                              hipStream_t stream) {
    (void)in_sizes; (void)n_in; (void)d_ws; (void)ws_size; (void)out_size;
    const float* hidden    = (const float*)d_in[0];
    const unsigned int* mk = (const unsigned int*)d_in[1];
    const float* mem_state = (const float*)d_in[2];
    const float* wq  = (const float*)d_in[3];
    const float* wk  = (const float*)d_in[4];
    const float* wv  = (const float*)d_in[5];
    const float* wo  = (const float*)d_in[6];
    const float* pre_s  = (const float*)d_in[7];
    const float* pre_b  = (const float*)d_in[8];
    const float* post_s = (const float*)d_in[9];
    const float* post_b = (const float*)d_in[10];
    float* out = (float*)d_out;

    k_transpose<<<dim3(16, 16), 256, 0, stream>>>(wq, 1024, 0);
    k_transpose<<<dim3(16, 8),  256, 0, stream>>>(wk, 512, 1);
    k_transpose<<<dim3(16, 8),  256, 0, stream>>>(wv, 512, 2);
    k_transpose<<<dim3(16, 16), 256, 0, stream>>>(wo, 1024, 3);
    k_rope<<<1, 128, 0, stream>>>();
    k_mask<<<1, 1024, 0, stream>>>(mk);
    k_ln_hx<<<NB * NMs * MBs, 256, 0, stream>>>(hidden, pre_s, pre_b);
    k_ln_init<<<NB * MEMm, 256, 0, stream>>>(mem_state, pre_s, pre_b);
    k_xkv0<<<256, 512, 0, stream>>>();
    k_loop<<<256, 512, 0, stream>>>(out, post_s, post_b, pre_s, pre_b);
}